// Round 17
// baseline (123.569 us; speedup 1.0000x reference)
//
#include <hip/hip_runtime.h>

typedef unsigned int u32;

static constexpr int HH = 1080, WW = 1920;
static constexpr int NPIX = HH * WW;            // 2,073,600
static constexpr int NVEC = NPIX / 4;           // 518,400 float4
static constexpr int NQ = 17;                   // supports split <= 16 (actual 10)
static constexpr int MAXOWN = 16;               // max distinct quantile hi-12 bins
static constexpr int OPB = 12;                  // owners per ph1 block (48 KB LDS) -> 1 pass for nown<=12
static constexpr int NGRP = 2;                  // owner groups (group 1 zeroes gh2, then no-ops if nown<=OPB)
static constexpr int NBLK = 512;                // grid for histA / scatter (must match!)
static constexpr int BT   = 1024;               // their block size
static constexpr int R1 = 16;                   // replicas for level-1 bin merge
static constexpr int NCH1 = 128;                // chunks for ph1 (4050 float4 each)
static constexpr int CH1V = NVEC / NCH1;        // 4050
static constexpr int TS = 64;                   // target tile size
static constexpr int TCX = WW / TS;             // 30
static constexpr int TCY = (HH + TS - 1) / TS;  // 17
static constexpr int NTILE = TCX * TCY;         // 510
static constexpr int NT512 = 512;

// ---- workspace layout (bytes; ws_size = 256 MB, plenty) ----
static constexpr size_t MIDS_OFF  = 0;     // float[32]
static constexpr size_t QB1_OFF   = 128;   // u32[32]
static constexpr size_t QR1_OFF   = 256;   // u32[32]
static constexpr size_t OIDX_OFF  = 384;   // u32[32]
static constexpr size_t OBIN_OFF  = 512;   // u32[32]
static constexpr size_t NOWN_OFF  = 640;   // u32[1]
static constexpr size_t KEY22_OFF = 768;   // u32[32]
static constexpr size_t R2O_OFF   = 896;   // u32[32]
static constexpr size_t TOT1_OFF  = 1024;                                   // u32[R1*4096]
static constexpr size_t GH2_OFF   = TOT1_OFF + (size_t)R1 * 4096 * 4;       // u32[NQ*1024] (zeroed by ph1 g==1)
static constexpr size_t ZRANGE    = GH2_OFF;                                // k_zero range: header+tot1 only
static constexpr size_t TCNT_OFF  = GH2_OFF + (size_t)NQ * 1024 * 4;        // u32[NBLK*512] fully written
static constexpr size_t TTOT_OFF  = TCNT_OFF + (size_t)NBLK * NT512 * 4;    // u32[512]
static constexpr size_t TBASE_OFF = TTOT_OFF + NT512 * 4;                   // u32[512]
static constexpr size_t TEND_OFF  = TBASE_OFF + NT512 * 4;                  // u32[512]
static constexpr size_t BASE2_OFF = TEND_OFF + NT512 * 4;                   // u32[NBLK*512] ([chunk][tile])
static constexpr size_t GH1_OFF   = BASE2_OFF + (size_t)NBLK * NT512 * 4;   // u32[MAXOWN*1024*NCH1] (TRANSPOSED [w][bin][c])
static constexpr size_t PAIRS_OFF = GH1_OFF + (size_t)MAXOWN * NCH1 * 1024 * 4; // uint2[NPIX]

static constexpr int ZVEC = (int)(ZRANGE / 16);
static constexpr int ZBLK = (ZVEC + 255) / 256;

// ---- zero header + tot1 (own kernel; runtime small-fill is pathological) ----
__global__ __launch_bounds__(256) void k_zero(float4* __restrict__ ws) {
    int i = blockIdx.x * 256 + threadIdx.x;
    if (i < ZVEC) ws[i] = make_float4(0.f, 0.f, 0.f, 0.f);
}

// ---- geometry helper: target pixel index, or -1 if dropped (flow-only) ----
__device__ __forceinline__ int target_of(int y, int x, float fx, float fy) {
    int ty = (int)rintf((float)y + fy);  // rintf = round-half-even = jnp.round
    int tx = (int)rintf((float)x + fx);
    if (ty < 0) ty += HH;                // JAX normalizes negative indices once
    if (tx < 0) tx += WW;
    if ((unsigned)ty >= (unsigned)HH || (unsigned)tx >= (unsigned)WW) return -1;
    return ty * WW + tx;
}

// ---- level 1: LDS 4096-bin histogram of bits[31:20] + per-(block,tile) target counts ----
__global__ __launch_bounds__(BT) void k_histA_cnt(const float* __restrict__ depth,
                                                  const float* __restrict__ flow,
                                                  u32* __restrict__ tot1,
                                                  u32* __restrict__ tcnt) {
    __shared__ u32 h[4096];
    __shared__ u32 tc[NT512];
    int tid = threadIdx.x;
    for (int j = tid; j < 4096; j += BT) h[j] = 0;
    for (int j = tid; j < NT512; j += BT) tc[j] = 0;
    __syncthreads();
    for (int v = blockIdx.x * BT + tid; v < NVEC; v += gridDim.x * BT) {
        int i = v * 4;
        float4 d4 = ((const float4*)depth)[v];
        float4 fa = ((const float4*)flow)[v * 2];
        float4 fb = ((const float4*)flow)[v * 2 + 1];
        int y = i / WW, x0 = i - y * WW;   // 4-group never crosses a row (WW%4==0)
        float dd[4] = {d4.x, d4.y, d4.z, d4.w};
        float fx[4] = {fa.x, fa.z, fb.x, fb.z};
        float fy[4] = {fa.y, fa.w, fb.y, fb.w};
        #pragma unroll
        for (int j = 0; j < 4; ++j) {
            if (dd[j] != 100.0f)                                   // sentinel excluded
                atomicAdd(&h[__float_as_uint(dd[j]) >> 20], 1u);   // d>0 -> monotonic bits
            int t = target_of(y, x0 + j, fx[j], fy[j]);
            if (t >= 0) {
                int ty = t / WW, tx = t - ty * WW;
                atomicAdd(&tc[(ty >> 6) * TCX + (tx >> 6)], 1u);
            }
        }
    }
    __syncthreads();
    u32 rep = blockIdx.x & (R1 - 1);
    for (int j = tid; j < 4096; j += BT) {
        u32 v = h[j];
        if (v) atomicAdd(&tot1[rep * 4096 + j], v);   // sparse, short chains
    }
    for (int j = tid; j < NT512; j += BT)
        tcnt[blockIdx.x * NT512 + j] = tc[j];         // non-atomic per-block counts
}

// ---- fused: blocks 0..511 per-tile chunk scan; block 512 quantile select ----
__global__ __launch_bounds__(512) void k_scan_sel(const u32* __restrict__ tcnt,
                                                  const u32* __restrict__ tot1,
                                                  const int* __restrict__ splitp,
                                                  u32* __restrict__ ttot, u32* __restrict__ base2,
                                                  u32* __restrict__ qb1, u32* __restrict__ qr1,
                                                  u32* __restrict__ oidx, u32* __restrict__ obin,
                                                  u32* __restrict__ nown) {
    __shared__ u32 s[512];
    __shared__ u32 qbS[NQ];
    __shared__ u32 totalsh;
    int tid = threadIdx.x;
    if (blockIdx.x < NT512) {
        // ---- tile scan: tile t, 512 chunk counts ----
        int t = blockIdx.x;
        u32 v = tcnt[tid * NT512 + t];
        s[tid] = v;
        __syncthreads();
        for (int off = 1; off < 512; off <<= 1) {
            u32 x = (tid >= off) ? s[tid - off] : 0;
            __syncthreads();
            s[tid] += x;
            __syncthreads();
        }
        base2[tid * NT512 + t] = s[tid] - v;     // [chunk][tile]: coalesced in scatter
        if (tid == 511) ttot[t] = s[511];
        return;
    }
    // ---- quantile select (8 bins/thread over merged 4096-bin hist) ----
    int split = *splitp;
    int base = tid * 8;
    u32 cc[8];
    #pragma unroll
    for (int k = 0; k < 8; ++k) cc[k] = 0;
    for (int r = 0; r < R1; ++r) {
        const u32* tp = tot1 + r * 4096 + base;
        #pragma unroll
        for (int k = 0; k < 8; ++k) cc[k] += tp[k];
    }
    u32 local = 0;
    #pragma unroll
    for (int k = 0; k < 8; ++k) local += cc[k];
    s[tid] = local;
    __syncthreads();
    for (int off = 1; off < 512; off <<= 1) {
        u32 x = (tid >= off) ? s[tid - off] : 0;
        __syncthreads();
        s[tid] += x;
        __syncthreads();
    }
    if (tid == 511) totalsh = s[511];
    __syncthreads();
    u32 l = totalsh;                 // valid-pixel count = histogram sum
    u32 step = l / (u32)split;
    u32 cum = s[tid] - local;        // exclusive prefix of this thread's 8 bins
    for (int k = 0; k < 8; ++k) {
        u32 c = cc[k];
        if (c) {
            for (int q = 0; q <= split; ++q) {
                u32 r = (q < split) ? (u32)q * step : l - 1u;
                if (r >= cum && r < cum + c) {
                    qb1[q] = (u32)(base + k);
                    qr1[q] = r - cum;
                    qbS[q] = (u32)(base + k);
                }
            }
        }
        cum += c;
    }
    __syncthreads();
    if (tid == 0) {   // owners: distinct (adjacent, ascending) hi-12 bins
        int w = -1;
        u32 prev = 0xFFFFFFFFu;
        for (int q = 0; q <= split; ++q) {
            if (qbS[q] != prev) { ++w; prev = qbS[q]; obin[w] = qbS[q]; }
            oidx[q] = (u32)w;
        }
        for (int w2 = w + 1; w2 < MAXOWN; ++w2) obin[w2] = 0xFFFFFFFFu;
        *nown = (u32)(w + 1);
    }
}

// ---- level 2: per-owner LDS hist of bits[19:10]; block = (chunk, 12-owner group) ----
// gh1 layout TRANSPOSED to [w][bin][c] so red1 reads are contiguous per thread.
// Group-1 blocks zero gh2 (frees k_zero of it), then no-op when nown <= OPB.
__global__ __launch_bounds__(1024) void k_ph1(const float* __restrict__ depth,
                                              const u32* __restrict__ obin,
                                              const u32* __restrict__ nownp,
                                              u32* __restrict__ ghist,
                                              u32* __restrict__ gh2) {
    int c = blockIdx.x / NGRP;          // chunk
    int g = blockIdx.x % NGRP;          // owner group
    int tid = threadIdx.x;
    if (g == 1) {                       // zero a 136-u32 slice of gh2 (17408 total / 128 chunks)
        int basez = c * 136;
        for (int j = tid; j < 136; j += 1024) {
            int idx = basez + j;
            if (idx < NQ * 1024) gh2[idx] = 0;
        }
    }
    int w0 = g * OPB;
    int nown = (int)*nownp;
    if (w0 >= nown) return;             // group 1 no-ops (after gh2 zeroing) when nown <= OPB
    __shared__ u32 h[OPB * 1024];       // 48 KB
    u32 ob[OPB];
    #pragma unroll
    for (int k = 0; k < OPB; ++k)
        ob[k] = (w0 + k < nown) ? obin[w0 + k] : 0xFFFFFFFFu;   // sentinel never matches
    for (int j = tid; j < OPB * 1024; j += 1024) h[j] = 0;
    __syncthreads();
    int lo = c * CH1V, hi = lo + CH1V;
    for (int v = lo + tid; v < hi; v += 1024) {
        float4 d4 = ((const float4*)depth)[v];
        float dd[4] = {d4.x, d4.y, d4.z, d4.w};
        #pragma unroll
        for (int j = 0; j < 4; ++j) {
            u32 bits = __float_as_uint(dd[j]);
            u32 b1 = bits >> 20;
            #pragma unroll
            for (int k = 0; k < OPB; ++k)
                if (ob[k] == b1)
                    atomicAdd(&h[k * 1024 + ((bits >> 10) & 1023u)], 1u);
        }
    }
    __syncthreads();
    for (int j = tid; j < OPB * 1024; j += 1024) {
        int k = j >> 10, bin = j & 1023;
        int w = w0 + k;
        if (w < nown)
            ghist[((size_t)w * 1024 + bin) * NCH1 + c] = h[j];   // [w][bin][c], strided write
    }
}

// ---- fused: blocks 0..split red1 (contiguous reads); block NQ tile-total prefix ----
__global__ __launch_bounds__(1024) void k_red1(const int* __restrict__ splitp,
                                               const u32* __restrict__ qb1,
                                               const u32* __restrict__ qr1,
                                               const u32* __restrict__ oidx,
                                               const u32* __restrict__ ghist,
                                               const u32* __restrict__ ttot,
                                               u32* __restrict__ key22, u32* __restrict__ r2o,
                                               u32* __restrict__ tbase, u32* __restrict__ tend) {
    __shared__ u32 part[1024];
    int tid = threadIdx.x;
    int b = blockIdx.x;
    if (b == NQ) {   // tile-total prefix sum (512 entries)
        u32 tv = (tid < NT512) ? ttot[tid] : 0;
        part[tid] = tv;
        __syncthreads();
        for (int off = 1; off < 1024; off <<= 1) {
            u32 x = (tid >= off) ? part[tid - off] : 0;
            __syncthreads();
            part[tid] += x;
            __syncthreads();
        }
        if (tid < NT512) {
            tbase[tid] = part[tid] - tv;
            tend[tid]  = part[tid];
        }
        return;
    }
    if (b > *splitp) return;
    int w = (int)oidx[b];
    // contiguous 512 B per thread: gh1[w][tid][0..127] as 32 x uint4
    const uint4* gp = (const uint4*)(ghist + ((size_t)w * 1024 + (u32)tid) * NCH1);
    u32 local = 0;
    #pragma unroll 8
    for (int c4 = 0; c4 < NCH1 / 4; ++c4) {
        uint4 u = gp[c4];
        local += u.x + u.y + u.z + u.w;
    }
    part[tid] = local;
    __syncthreads();
    for (int off = 1; off < 1024; off <<= 1) {
        u32 x = (tid >= off) ? part[tid - off] : 0;
        __syncthreads();
        part[tid] += x;
        __syncthreads();
    }
    u32 target = qr1[b];
    u32 cum = part[tid] - local;
    if (local && target >= cum && target < cum + local) {
        key22[b] = (qb1[b] << 10) | (u32)tid;
        r2o[b] = target - cum;
    }
}

// ---- level 3: low-10-bit histogram restricted to 22-bit keys (tiny atomic count) ----
__global__ __launch_bounds__(256) void k_ph2(const float* __restrict__ depth,
                                             const int* __restrict__ splitp,
                                             const u32* __restrict__ key22,
                                             u32* __restrict__ gh2) {
    __shared__ u32 k22[NQ];
    int tid = threadIdx.x, split = *splitp;
    if (tid < NQ) k22[tid] = (tid <= split) ? key22[tid] : 0xFFFFFFFFu;
    __syncthreads();
    for (int v = blockIdx.x * blockDim.x + tid; v < NVEC; v += gridDim.x * blockDim.x) {
        float4 d4 = ((const float4*)depth)[v];
        float dd[4] = {d4.x, d4.y, d4.z, d4.w};
        #pragma unroll
        for (int j = 0; j < 4; ++j) {
            if (dd[j] != 100.0f) {
                u32 bits = __float_as_uint(dd[j]);
                u32 hi22 = bits >> 10;
                for (int q = 0; q <= split; ++q)
                    if (k22[q] == hi22) atomicAdd(&gh2[q * 1024 + (bits & 1023u)], 1u);
            }
        }
    }
}

// ---- level-3 reduce: exact order-statistic floats ----
__global__ __launch_bounds__(1024) void k_red2(const int* __restrict__ splitp,
                                               const u32* __restrict__ key22,
                                               const u32* __restrict__ r2o,
                                               const u32* __restrict__ gh2,
                                               float* __restrict__ mids) {
    int q = blockIdx.x;
    if (q > *splitp) return;
    __shared__ u32 part[1024];
    int tid = threadIdx.x;
    u32 local = gh2[q * 1024 + tid];
    part[tid] = local;
    __syncthreads();
    for (int off = 1; off < 1024; off <<= 1) {
        u32 v = (tid >= off) ? part[tid - off] : 0;
        __syncthreads();
        part[tid] += v;
        __syncthreads();
    }
    u32 target = r2o[q];
    u32 cum = part[tid] - local;
    if (local && target >= cum && target < cum + local)
        mids[q] = __uint_as_float((key22[q] << 10) | (u32)tid);
}

// ---- scatter: exact-base pair writes, zero device atomics, no inner barriers ----
__global__ __launch_bounds__(BT) void k_scatter(const float* __restrict__ depth,
                                                const float* __restrict__ flow,
                                                const int* __restrict__ splitp,
                                                const float* __restrict__ mids,
                                                const u32* __restrict__ tbase,
                                                const u32* __restrict__ base2,
                                                uint2* __restrict__ pairs) {
    __shared__ u32 cur[NT512];
    __shared__ float msh[NQ];
    int tid = threadIdx.x, split = *splitp;
    if (tid < NQ) msh[tid] = (tid <= split) ? mids[tid] : 0.f;
    if (tid < NT512) cur[tid] = tbase[tid] + base2[blockIdx.x * NT512 + tid];   // coalesced
    __syncthreads();
    for (int v = blockIdx.x * BT + tid; v < NVEC; v += gridDim.x * BT) {   // = histA traversal
        int i = v * 4;
        float4 d4 = ((const float4*)depth)[v];
        float4 fa = ((const float4*)flow)[v * 2];
        float4 fb = ((const float4*)flow)[v * 2 + 1];
        int y = i / WW, x0 = i - y * WW;
        float dd[4] = {d4.x, d4.y, d4.z, d4.w};
        float fx[4] = {fa.x, fa.z, fb.x, fb.z};
        float fy[4] = {fa.y, fa.w, fb.y, fb.w};
        #pragma unroll
        for (int j = 0; j < 4; ++j) {
            int t = target_of(y, x0 + j, fx[j], fy[j]);
            if (t < 0) continue;                      // only this drop counted by histA too
            float d = dd[j];
            int rank = -1;
            for (int k = 1; k <= split; ++k)
                if (d >= msh[k - 1] && d < msh[k]) { rank = split - k; break; }
            // far bins = low rank; within bin, last row-major source wins.
            // rank<0 (d==max or sentinel): p=0 dummy keeps segments dense, never wins.
            u32 p = (rank >= 0) ? (u32)rank * (u32)NPIX + (u32)(i + j) + 1u : 0u;
            int ty = t / WW, tx = t - ty * WW;
            int tile = (ty >> 6) * TCX + (tx >> 6);
            u32 pos = atomicAdd(&cur[tile], 1u);      // LDS only
            pairs[pos] = make_uint2((u32)t, p);
        }
    }
}

// ---- per-tile LDS z-buffer reduce + output write (contiguous segments) ----
__global__ __launch_bounds__(1024) void k_tile_reduce(const uint2* __restrict__ pairs,
                                                      const u32* __restrict__ tbase,
                                                      const u32* __restrict__ tend,
                                                      const float* __restrict__ img,
                                                      float* __restrict__ out) {
    __shared__ u32 zb[TS * TS];
    int tid = threadIdx.x;
    int tile = blockIdx.x;
    for (int c = tid; c < TS * TS; c += 1024) zb[c] = 0;
    __syncthreads();
    int ty0 = (tile / TCX) << 6, tx0 = (tile % TCX) << 6;
    u32 b = tbase[tile], e = tend[tile];
    for (u32 k = b + tid; k < e; k += 1024) {
        uint2 pr = pairs[k];
        int t = (int)pr.x;
        int ty = t / WW, tx = t - ty * WW;
        atomicMax(&zb[((ty - ty0) << 6) | (tx - tx0)], pr.y);   // LDS
    }
    __syncthreads();
    for (int c = tid; c < TS * TS; c += 1024) {
        int ty = ty0 + (c >> 6);
        if (ty >= HH) continue;
        int tx = tx0 + (c & 63);
        u32 p = zb[c];
        float r = 0.f, g = 0.f, bl = 0.f;
        if (p) {
            u32 src = (p - 1u) % (u32)NPIX;   // p-1 = rank*NPIX + src
            r  = img[src * 3 + 0];
            g  = img[src * 3 + 1];
            bl = img[src * 3 + 2];
        }
        int t = ty * WW + tx;
        out[t * 3 + 0] = r;
        out[t * 3 + 1] = g;
        out[t * 3 + 2] = bl;
    }
}

extern "C" void kernel_launch(void* const* d_in, const int* in_sizes, int n_in,
                              void* d_out, int out_size, void* d_ws, size_t ws_size,
                              hipStream_t stream) {
    const float* img    = (const float*)d_in[0];
    const float* flow   = (const float*)d_in[1];   // [1,H,W,2] flat == [H,W,2]
    const float* depth  = (const float*)d_in[2];
    const int*   splitp = (const int*)d_in[3];

    char* ws = (char*)d_ws;
    float* mids  = (float*)(ws + MIDS_OFF);
    u32*   qb1   = (u32*)(ws + QB1_OFF);
    u32*   qr1   = (u32*)(ws + QR1_OFF);
    u32*   oidx  = (u32*)(ws + OIDX_OFF);
    u32*   obin  = (u32*)(ws + OBIN_OFF);
    u32*   nown  = (u32*)(ws + NOWN_OFF);
    u32*   key22 = (u32*)(ws + KEY22_OFF);
    u32*   r2o   = (u32*)(ws + R2O_OFF);
    u32*   tot1  = (u32*)(ws + TOT1_OFF);
    u32*   gh2   = (u32*)(ws + GH2_OFF);
    u32*   tcnt  = (u32*)(ws + TCNT_OFF);
    u32*   ttot  = (u32*)(ws + TTOT_OFF);
    u32*   tbase = (u32*)(ws + TBASE_OFF);
    u32*   tend  = (u32*)(ws + TEND_OFF);
    u32*   base2 = (u32*)(ws + BASE2_OFF);
    u32*   gh1   = (u32*)(ws + GH1_OFF);
    uint2* pairs = (uint2*)(ws + PAIRS_OFF);
    float* out   = (float*)d_out;

    k_zero       <<<ZBLK, 256, 0, stream>>>((float4*)d_ws);
    k_histA_cnt  <<<NBLK, BT, 0, stream>>>(depth, flow, tot1, tcnt);
    k_scan_sel   <<<NT512 + 1, 512, 0, stream>>>(tcnt, tot1, splitp, ttot, base2,
                                                 qb1, qr1, oidx, obin, nown);
    k_ph1        <<<NCH1 * NGRP, 1024, 0, stream>>>(depth, obin, nown, gh1, gh2);
    k_red1       <<<NQ + 1, 1024, 0, stream>>>(splitp, qb1, qr1, oidx, gh1, ttot,
                                               key22, r2o, tbase, tend);
    k_ph2        <<<2048, 256, 0, stream>>>(depth, splitp, key22, gh2);
    k_red2       <<<NQ, 1024, 0, stream>>>(splitp, key22, r2o, gh2, mids);
    k_scatter    <<<NBLK, BT, 0, stream>>>(depth, flow, splitp, mids, tbase, base2, pairs);
    k_tile_reduce<<<NTILE, 1024, 0, stream>>>(pairs, tbase, tend, img, out);
}

// Round 18
// 94.978 us; speedup vs baseline: 1.3010x; 1.3010x over previous
//
#include <hip/hip_runtime.h>

typedef unsigned int u32;

static constexpr int HH = 1080, WW = 1920;
static constexpr int NPIX = HH * WW;            // 2,073,600
static constexpr int NVEC = NPIX / 4;           // 518,400 float4
static constexpr int NQ = 17;                   // supports split <= 16 (actual 10)
static constexpr int MAXOWN = 16;               // max distinct quantile hi-12 bins
static constexpr int OPB = 8;                   // owners per ph1 block (32 KB LDS)
static constexpr int NGRP = MAXOWN / OPB;       // 2 owner groups
static constexpr int NBLK = 512;                // grid for histA / scatter (must match!)
static constexpr int BT   = 1024;               // their block size
static constexpr int R1 = 16;                   // replicas for level-1 bin merge
static constexpr int NCH1 = 128;                // chunks for ph1 (4050 float4 each)
static constexpr int CH1V = NVEC / NCH1;        // 4050
static constexpr int TS = 64;                   // target tile size
static constexpr int TCX = WW / TS;             // 30
static constexpr int TCY = (HH + TS - 1) / TS;  // 17
static constexpr int NTILE = TCX * TCY;         // 510
static constexpr int NT512 = 512;

// ---- workspace layout (bytes; ws_size = 256 MB, plenty) ----
static constexpr size_t MIDS_OFF  = 0;     // float[32]
static constexpr size_t QB1_OFF   = 128;   // u32[32]
static constexpr size_t QR1_OFF   = 256;   // u32[32]
static constexpr size_t OIDX_OFF  = 384;   // u32[32]
static constexpr size_t OBIN_OFF  = 512;   // u32[32]
static constexpr size_t NOWN_OFF  = 640;   // u32[1]
static constexpr size_t KEY22_OFF = 768;   // u32[32]
static constexpr size_t R2O_OFF   = 896;   // u32[32]
static constexpr size_t TOT1_OFF  = 1024;                                   // u32[R1*4096]
static constexpr size_t GH2_OFF   = TOT1_OFF + (size_t)R1 * 4096 * 4;       // u32[NQ*1024]
static constexpr size_t ZERO_BYTES = GH2_OFF + (size_t)NQ * 1024 * 4;       // ~333 KB
static constexpr size_t TCNT_OFF  = ZERO_BYTES;                             // u32[NBLK*512] fully written
static constexpr size_t TTOT_OFF  = TCNT_OFF + (size_t)NBLK * NT512 * 4;    // u32[512]
static constexpr size_t TBASE_OFF = TTOT_OFF + NT512 * 4;                   // u32[512]
static constexpr size_t TEND_OFF  = TBASE_OFF + NT512 * 4;                  // u32[512]
static constexpr size_t BASE2_OFF = TEND_OFF + NT512 * 4;                   // u32[NBLK*512] ([chunk][tile])
static constexpr size_t GH1_OFF   = BASE2_OFF + (size_t)NBLK * NT512 * 4;   // u32[MAXOWN*NCH1*1024]
static constexpr size_t PAIRS_OFF = GH1_OFF + (size_t)MAXOWN * NCH1 * 1024 * 4; // uint2[NPIX]

static constexpr int ZVEC = (int)(ZERO_BYTES / 16);
static constexpr int ZBLK = (ZVEC + 255) / 256;

// ---- zero header + tot1 + gh2 (own kernel; runtime small-fill is pathological) ----
__global__ __launch_bounds__(256) void k_zero(float4* __restrict__ ws) {
    int i = blockIdx.x * 256 + threadIdx.x;
    if (i < ZVEC) ws[i] = make_float4(0.f, 0.f, 0.f, 0.f);
}

// ---- geometry helper: target pixel index, or -1 if dropped (flow-only) ----
__device__ __forceinline__ int target_of(int y, int x, float fx, float fy) {
    int ty = (int)rintf((float)y + fy);  // rintf = round-half-even = jnp.round
    int tx = (int)rintf((float)x + fx);
    if (ty < 0) ty += HH;                // JAX normalizes negative indices once
    if (tx < 0) tx += WW;
    if ((unsigned)ty >= (unsigned)HH || (unsigned)tx >= (unsigned)WW) return -1;
    return ty * WW + tx;
}

// ---- level 1: LDS 4096-bin histogram of bits[31:20] + per-(block,tile) target counts ----
__global__ __launch_bounds__(BT) void k_histA_cnt(const float* __restrict__ depth,
                                                  const float* __restrict__ flow,
                                                  u32* __restrict__ tot1,
                                                  u32* __restrict__ tcnt) {
    __shared__ u32 h[4096];
    __shared__ u32 tc[NT512];
    int tid = threadIdx.x;
    for (int j = tid; j < 4096; j += BT) h[j] = 0;
    for (int j = tid; j < NT512; j += BT) tc[j] = 0;
    __syncthreads();
    for (int v = blockIdx.x * BT + tid; v < NVEC; v += gridDim.x * BT) {
        int i = v * 4;
        float4 d4 = ((const float4*)depth)[v];
        float4 fa = ((const float4*)flow)[v * 2];
        float4 fb = ((const float4*)flow)[v * 2 + 1];
        int y = i / WW, x0 = i - y * WW;   // 4-group never crosses a row (WW%4==0)
        float dd[4] = {d4.x, d4.y, d4.z, d4.w};
        float fx[4] = {fa.x, fa.z, fb.x, fb.z};
        float fy[4] = {fa.y, fa.w, fb.y, fb.w};
        #pragma unroll
        for (int j = 0; j < 4; ++j) {
            if (dd[j] != 100.0f)                                   // sentinel excluded
                atomicAdd(&h[__float_as_uint(dd[j]) >> 20], 1u);   // d>0 -> monotonic bits
            int t = target_of(y, x0 + j, fx[j], fy[j]);
            if (t >= 0) {
                int ty = t / WW, tx = t - ty * WW;
                atomicAdd(&tc[(ty >> 6) * TCX + (tx >> 6)], 1u);
            }
        }
    }
    __syncthreads();
    u32 rep = blockIdx.x & (R1 - 1);
    for (int j = tid; j < 4096; j += BT) {
        u32 v = h[j];
        if (v) atomicAdd(&tot1[rep * 4096 + j], v);   // sparse, short chains
    }
    for (int j = tid; j < NT512; j += BT)
        tcnt[blockIdx.x * NT512 + j] = tc[j];         // non-atomic per-block counts
}

// ---- fused: blocks 0..511 per-tile chunk scan; block 512 quantile select ----
__global__ __launch_bounds__(512) void k_scan_sel(const u32* __restrict__ tcnt,
                                                  const u32* __restrict__ tot1,
                                                  const int* __restrict__ splitp,
                                                  u32* __restrict__ ttot, u32* __restrict__ base2,
                                                  u32* __restrict__ qb1, u32* __restrict__ qr1,
                                                  u32* __restrict__ oidx, u32* __restrict__ obin,
                                                  u32* __restrict__ nown) {
    __shared__ u32 s[512];
    __shared__ u32 qbS[NQ];
    __shared__ u32 totalsh;
    int tid = threadIdx.x;
    if (blockIdx.x < NT512) {
        // ---- tile scan: tile t, 512 chunk counts ----
        int t = blockIdx.x;
        u32 v = tcnt[tid * NT512 + t];
        s[tid] = v;
        __syncthreads();
        for (int off = 1; off < 512; off <<= 1) {
            u32 x = (tid >= off) ? s[tid - off] : 0;
            __syncthreads();
            s[tid] += x;
            __syncthreads();
        }
        base2[tid * NT512 + t] = s[tid] - v;     // [chunk][tile]: coalesced in scatter
        if (tid == 511) ttot[t] = s[511];
        return;
    }
    // ---- quantile select (8 bins/thread over merged 4096-bin hist) ----
    int split = *splitp;
    int base = tid * 8;
    u32 cc[8];
    #pragma unroll
    for (int k = 0; k < 8; ++k) cc[k] = 0;
    for (int r = 0; r < R1; ++r) {
        const u32* tp = tot1 + r * 4096 + base;
        #pragma unroll
        for (int k = 0; k < 8; ++k) cc[k] += tp[k];
    }
    u32 local = 0;
    #pragma unroll
    for (int k = 0; k < 8; ++k) local += cc[k];
    s[tid] = local;
    __syncthreads();
    for (int off = 1; off < 512; off <<= 1) {
        u32 x = (tid >= off) ? s[tid - off] : 0;
        __syncthreads();
        s[tid] += x;
        __syncthreads();
    }
    if (tid == 511) totalsh = s[511];
    __syncthreads();
    u32 l = totalsh;                 // valid-pixel count = histogram sum
    u32 step = l / (u32)split;
    u32 cum = s[tid] - local;        // exclusive prefix of this thread's 8 bins
    for (int k = 0; k < 8; ++k) {
        u32 c = cc[k];
        if (c) {
            for (int q = 0; q <= split; ++q) {
                u32 r = (q < split) ? (u32)q * step : l - 1u;
                if (r >= cum && r < cum + c) {
                    qb1[q] = (u32)(base + k);
                    qr1[q] = r - cum;
                    qbS[q] = (u32)(base + k);
                }
            }
        }
        cum += c;
    }
    __syncthreads();
    if (tid == 0) {   // owners: distinct (adjacent, ascending) hi-12 bins
        int w = -1;
        u32 prev = 0xFFFFFFFFu;
        for (int q = 0; q <= split; ++q) {
            if (qbS[q] != prev) { ++w; prev = qbS[q]; obin[w] = qbS[q]; }
            oidx[q] = (u32)w;
        }
        for (int w2 = w + 1; w2 < MAXOWN; ++w2) obin[w2] = 0xFFFFFFFFu;
        *nown = (u32)(w + 1);
    }
}

// ---- level 2: per-owner LDS hist of bits[19:10]; one block = (chunk, 8-owner group) ----
__global__ __launch_bounds__(1024) void k_ph1(const float* __restrict__ depth,
                                              const u32* __restrict__ obin,
                                              const u32* __restrict__ nownp,
                                              u32* __restrict__ ghist) {
    int c = blockIdx.x / NGRP;          // chunk
    int g = blockIdx.x % NGRP;          // owner group
    int w0 = g * OPB;
    int nown = (int)*nownp;
    if (w0 >= nown) return;
    __shared__ u32 h[OPB * 1024];       // 32 KB
    int tid = threadIdx.x;
    u32 ob[OPB];
    #pragma unroll
    for (int k = 0; k < OPB; ++k)
        ob[k] = (w0 + k < nown) ? obin[w0 + k] : 0xFFFFFFFFu;   // sentinel never matches
    for (int j = tid; j < OPB * 1024; j += 1024) h[j] = 0;
    __syncthreads();
    int lo = c * CH1V, hi = lo + CH1V;
    for (int v = lo + tid; v < hi; v += 1024) {
        float4 d4 = ((const float4*)depth)[v];
        float dd[4] = {d4.x, d4.y, d4.z, d4.w};
        #pragma unroll
        for (int j = 0; j < 4; ++j) {
            u32 bits = __float_as_uint(dd[j]);
            u32 b1 = bits >> 20;
            #pragma unroll
            for (int k = 0; k < OPB; ++k)
                if (ob[k] == b1)
                    atomicAdd(&h[k * 1024 + ((bits >> 10) & 1023u)], 1u);
        }
    }
    __syncthreads();
    for (int j = tid; j < OPB * 1024; j += 1024) {
        int k = j >> 10, bin = j & 1023;
        int w = w0 + k;
        if (w < nown) ghist[(w * NCH1 + c) * 1024 + bin] = h[j];   // non-atomic, coalesced
    }
}

// ---- fused: blocks 0..split red1; block NQ does tile-total prefix -> tbase/tend ----
__global__ __launch_bounds__(1024) void k_red1(const int* __restrict__ splitp,
                                               const u32* __restrict__ qb1,
                                               const u32* __restrict__ qr1,
                                               const u32* __restrict__ oidx,
                                               const u32* __restrict__ ghist,
                                               const u32* __restrict__ ttot,
                                               u32* __restrict__ key22, u32* __restrict__ r2o,
                                               u32* __restrict__ tbase, u32* __restrict__ tend) {
    __shared__ u32 part[1024];
    int tid = threadIdx.x;
    int b = blockIdx.x;
    if (b == NQ) {   // tile-total prefix sum (512 entries)
        u32 tv = (tid < NT512) ? ttot[tid] : 0;
        part[tid] = tv;
        __syncthreads();
        for (int off = 1; off < 1024; off <<= 1) {
            u32 x = (tid >= off) ? part[tid - off] : 0;
            __syncthreads();
            part[tid] += x;
            __syncthreads();
        }
        if (tid < NT512) {
            tbase[tid] = part[tid] - tv;
            tend[tid]  = part[tid];
        }
        return;
    }
    if (b > *splitp) return;
    int w = (int)oidx[b];
    u32 local = 0;
    for (int c = 0; c < NCH1; ++c) local += ghist[(w * NCH1 + c) * 1024 + tid];
    part[tid] = local;
    __syncthreads();
    for (int off = 1; off < 1024; off <<= 1) {
        u32 x = (tid >= off) ? part[tid - off] : 0;
        __syncthreads();
        part[tid] += x;
        __syncthreads();
    }
    u32 target = qr1[b];
    u32 cum = part[tid] - local;
    if (local && target >= cum && target < cum + local) {
        key22[b] = (qb1[b] << 10) | (u32)tid;
        r2o[b] = target - cum;
    }
}

// ---- level 3: low-10-bit histogram restricted to 22-bit keys (tiny atomic count) ----
__global__ __launch_bounds__(256) void k_ph2(const float* __restrict__ depth,
                                             const int* __restrict__ splitp,
                                             const u32* __restrict__ key22,
                                             u32* __restrict__ gh2) {
    __shared__ u32 k22[NQ];
    int tid = threadIdx.x, split = *splitp;
    if (tid < NQ) k22[tid] = (tid <= split) ? key22[tid] : 0xFFFFFFFFu;
    __syncthreads();
    for (int v = blockIdx.x * blockDim.x + tid; v < NVEC; v += gridDim.x * blockDim.x) {
        float4 d4 = ((const float4*)depth)[v];
        float dd[4] = {d4.x, d4.y, d4.z, d4.w};
        #pragma unroll
        for (int j = 0; j < 4; ++j) {
            if (dd[j] != 100.0f) {
                u32 bits = __float_as_uint(dd[j]);
                u32 hi22 = bits >> 10;
                for (int q = 0; q <= split; ++q)
                    if (k22[q] == hi22) atomicAdd(&gh2[q * 1024 + (bits & 1023u)], 1u);
            }
        }
    }
}

// ---- level-3 reduce: exact order-statistic floats ----
__global__ __launch_bounds__(1024) void k_red2(const int* __restrict__ splitp,
                                               const u32* __restrict__ key22,
                                               const u32* __restrict__ r2o,
                                               const u32* __restrict__ gh2,
                                               float* __restrict__ mids) {
    int q = blockIdx.x;
    if (q > *splitp) return;
    __shared__ u32 part[1024];
    int tid = threadIdx.x;
    u32 local = gh2[q * 1024 + tid];
    part[tid] = local;
    __syncthreads();
    for (int off = 1; off < 1024; off <<= 1) {
        u32 v = (tid >= off) ? part[tid - off] : 0;
        __syncthreads();
        part[tid] += v;
        __syncthreads();
    }
    u32 target = r2o[q];
    u32 cum = part[tid] - local;
    if (local && target >= cum && target < cum + local)
        mids[q] = __uint_as_float((key22[q] << 10) | (u32)tid);
}

// ---- scatter: exact-base pair writes, zero device atomics, no inner barriers ----
__global__ __launch_bounds__(BT) void k_scatter(const float* __restrict__ depth,
                                                const float* __restrict__ flow,
                                                const int* __restrict__ splitp,
                                                const float* __restrict__ mids,
                                                const u32* __restrict__ tbase,
                                                const u32* __restrict__ base2,
                                                uint2* __restrict__ pairs) {
    __shared__ u32 cur[NT512];
    __shared__ float msh[NQ];
    int tid = threadIdx.x, split = *splitp;
    if (tid < NQ) msh[tid] = (tid <= split) ? mids[tid] : 0.f;
    if (tid < NT512) cur[tid] = tbase[tid] + base2[blockIdx.x * NT512 + tid];   // coalesced
    __syncthreads();
    for (int v = blockIdx.x * BT + tid; v < NVEC; v += gridDim.x * BT) {   // = histA traversal
        int i = v * 4;
        float4 d4 = ((const float4*)depth)[v];
        float4 fa = ((const float4*)flow)[v * 2];
        float4 fb = ((const float4*)flow)[v * 2 + 1];
        int y = i / WW, x0 = i - y * WW;
        float dd[4] = {d4.x, d4.y, d4.z, d4.w};
        float fx[4] = {fa.x, fa.z, fb.x, fb.z};
        float fy[4] = {fa.y, fa.w, fb.y, fb.w};
        #pragma unroll
        for (int j = 0; j < 4; ++j) {
            int t = target_of(y, x0 + j, fx[j], fy[j]);
            if (t < 0) continue;                      // only this drop counted by histA too
            float d = dd[j];
            int rank = -1;
            for (int k = 1; k <= split; ++k)
                if (d >= msh[k - 1] && d < msh[k]) { rank = split - k; break; }
            // far bins = low rank; within bin, last row-major source wins.
            // rank<0 (d==max or sentinel): p=0 dummy keeps segments dense, never wins.
            u32 p = (rank >= 0) ? (u32)rank * (u32)NPIX + (u32)(i + j) + 1u : 0u;
            int ty = t / WW, tx = t - ty * WW;
            int tile = (ty >> 6) * TCX + (tx >> 6);
            u32 pos = atomicAdd(&cur[tile], 1u);      // LDS only
            pairs[pos] = make_uint2((u32)t, p);
        }
    }
}

// ---- per-tile LDS z-buffer reduce + output write (contiguous segments) ----
__global__ __launch_bounds__(1024) void k_tile_reduce(const uint2* __restrict__ pairs,
                                                      const u32* __restrict__ tbase,
                                                      const u32* __restrict__ tend,
                                                      const float* __restrict__ img,
                                                      float* __restrict__ out) {
    __shared__ u32 zb[TS * TS];
    int tid = threadIdx.x;
    int tile = blockIdx.x;
    for (int c = tid; c < TS * TS; c += 1024) zb[c] = 0;
    __syncthreads();
    int ty0 = (tile / TCX) << 6, tx0 = (tile % TCX) << 6;
    u32 b = tbase[tile], e = tend[tile];
    for (u32 k = b + tid; k < e; k += 1024) {
        uint2 pr = pairs[k];
        int t = (int)pr.x;
        int ty = t / WW, tx = t - ty * WW;
        atomicMax(&zb[((ty - ty0) << 6) | (tx - tx0)], pr.y);   // LDS
    }
    __syncthreads();
    for (int c = tid; c < TS * TS; c += 1024) {
        int ty = ty0 + (c >> 6);
        if (ty >= HH) continue;
        int tx = tx0 + (c & 63);
        u32 p = zb[c];
        float r = 0.f, g = 0.f, bl = 0.f;
        if (p) {
            u32 src = (p - 1u) % (u32)NPIX;   // p-1 = rank*NPIX + src
            r  = img[src * 3 + 0];
            g  = img[src * 3 + 1];
            bl = img[src * 3 + 2];
        }
        int t = ty * WW + tx;
        out[t * 3 + 0] = r;
        out[t * 3 + 1] = g;
        out[t * 3 + 2] = bl;
    }
}

extern "C" void kernel_launch(void* const* d_in, const int* in_sizes, int n_in,
                              void* d_out, int out_size, void* d_ws, size_t ws_size,
                              hipStream_t stream) {
    const float* img    = (const float*)d_in[0];
    const float* flow   = (const float*)d_in[1];   // [1,H,W,2] flat == [H,W,2]
    const float* depth  = (const float*)d_in[2];
    const int*   splitp = (const int*)d_in[3];

    char* ws = (char*)d_ws;
    float* mids  = (float*)(ws + MIDS_OFF);
    u32*   qb1   = (u32*)(ws + QB1_OFF);
    u32*   qr1   = (u32*)(ws + QR1_OFF);
    u32*   oidx  = (u32*)(ws + OIDX_OFF);
    u32*   obin  = (u32*)(ws + OBIN_OFF);
    u32*   nown  = (u32*)(ws + NOWN_OFF);
    u32*   key22 = (u32*)(ws + KEY22_OFF);
    u32*   r2o   = (u32*)(ws + R2O_OFF);
    u32*   tot1  = (u32*)(ws + TOT1_OFF);
    u32*   gh2   = (u32*)(ws + GH2_OFF);
    u32*   tcnt  = (u32*)(ws + TCNT_OFF);
    u32*   ttot  = (u32*)(ws + TTOT_OFF);
    u32*   tbase = (u32*)(ws + TBASE_OFF);
    u32*   tend  = (u32*)(ws + TEND_OFF);
    u32*   base2 = (u32*)(ws + BASE2_OFF);
    u32*   gh1   = (u32*)(ws + GH1_OFF);
    uint2* pairs = (uint2*)(ws + PAIRS_OFF);
    float* out   = (float*)d_out;

    k_zero       <<<ZBLK, 256, 0, stream>>>((float4*)d_ws);
    k_histA_cnt  <<<NBLK, BT, 0, stream>>>(depth, flow, tot1, tcnt);
    k_scan_sel   <<<NT512 + 1, 512, 0, stream>>>(tcnt, tot1, splitp, ttot, base2,
                                                 qb1, qr1, oidx, obin, nown);
    k_ph1        <<<NCH1 * NGRP, 1024, 0, stream>>>(depth, obin, nown, gh1);
    k_red1       <<<NQ + 1, 1024, 0, stream>>>(splitp, qb1, qr1, oidx, gh1, ttot,
                                               key22, r2o, tbase, tend);
    k_ph2        <<<2048, 256, 0, stream>>>(depth, splitp, key22, gh2);
    k_red2       <<<NQ, 1024, 0, stream>>>(splitp, key22, r2o, gh2, mids);
    k_scatter    <<<NBLK, BT, 0, stream>>>(depth, flow, splitp, mids, tbase, base2, pairs);
    k_tile_reduce<<<NTILE, 1024, 0, stream>>>(pairs, tbase, tend, img, out);
}

// Round 19
// 93.312 us; speedup vs baseline: 1.3243x; 1.0179x over previous
//
#include <hip/hip_runtime.h>

typedef unsigned int u32;

static constexpr int HH = 1080, WW = 1920;
static constexpr int NPIX = HH * WW;            // 2,073,600
static constexpr int NVEC = NPIX / 4;           // 518,400 float4
static constexpr int NQ = 17;                   // supports split <= 16 (actual 10)
static constexpr int MAXOWN = 16;               // max distinct quantile hi-12 bins
static constexpr int OPB = 8;                   // owners per ph1 block (32 KB LDS)
static constexpr int NGRP = MAXOWN / OPB;       // 2 owner groups
static constexpr int NBLK = 512;                // grid for histA / scatter (must match!)
static constexpr int BT   = 1024;               // their block size
static constexpr int R1 = 16;                   // replicas for level-1 bin merge
static constexpr int NCH1 = 128;                // chunks for ph1 (4050 float4 each)
static constexpr int CH1V = NVEC / NCH1;        // 4050
static constexpr int TS = 64;                   // target tile size
static constexpr int TCX = WW / TS;             // 30
static constexpr int TCY = (HH + TS - 1) / TS;  // 17
static constexpr int NTILE = TCX * TCY;         // 510
static constexpr int NT512 = 512;

// ---- workspace layout (bytes; ws_size = 256 MB, plenty) ----
static constexpr size_t MIDS_OFF  = 0;     // float[32]
static constexpr size_t QB1_OFF   = 128;   // u32[32]
static constexpr size_t QR1_OFF   = 256;   // u32[32]
static constexpr size_t OIDX_OFF  = 384;   // u32[32]
static constexpr size_t OBIN_OFF  = 512;   // u32[32]
static constexpr size_t NOWN_OFF  = 640;   // u32[1]
static constexpr size_t KEY22_OFF = 768;   // u32[32]
static constexpr size_t R2O_OFF   = 896;   // u32[32]
static constexpr size_t TOT1_OFF  = 1024;                                   // u32[R1*4096]
static constexpr size_t GH2_OFF   = TOT1_OFF + (size_t)R1 * 4096 * 4;       // u32[NQ*1024]
static constexpr size_t ZERO_BYTES = GH2_OFF + (size_t)NQ * 1024 * 4;       // ~333 KB
static constexpr size_t TCNT_OFF  = ZERO_BYTES;                             // u32[NBLK*512] fully written
static constexpr size_t TTOT_OFF  = TCNT_OFF + (size_t)NBLK * NT512 * 4;    // u32[512]
static constexpr size_t TBASE_OFF = TTOT_OFF + NT512 * 4;                   // u32[512]
static constexpr size_t TEND_OFF  = TBASE_OFF + NT512 * 4;                  // u32[512]
static constexpr size_t BASE2_OFF = TEND_OFF + NT512 * 4;                   // u32[NBLK*512] ([chunk][tile])
static constexpr size_t GH1_OFF   = BASE2_OFF + (size_t)NBLK * NT512 * 4;   // u32[MAXOWN*NCH1*1024]
static constexpr size_t PAIRS_OFF = GH1_OFF + (size_t)MAXOWN * NCH1 * 1024 * 4; // uint2[NPIX]

static constexpr int ZVEC = (int)(ZERO_BYTES / 16);
static constexpr int ZBLK = (ZVEC + 255) / 256;

// ---- zero header + tot1 + gh2 (own kernel; runtime small-fill is pathological) ----
__global__ __launch_bounds__(256) void k_zero(float4* __restrict__ ws) {
    int i = blockIdx.x * 256 + threadIdx.x;
    if (i < ZVEC) ws[i] = make_float4(0.f, 0.f, 0.f, 0.f);
}

// ---- geometry helper: target pixel index, or -1 if dropped (flow-only) ----
__device__ __forceinline__ int target_of(int y, int x, float fx, float fy) {
    int ty = (int)rintf((float)y + fy);  // rintf = round-half-even = jnp.round
    int tx = (int)rintf((float)x + fx);
    if (ty < 0) ty += HH;                // JAX normalizes negative indices once
    if (tx < 0) tx += WW;
    if ((unsigned)ty >= (unsigned)HH || (unsigned)tx >= (unsigned)WW) return -1;
    return ty * WW + tx;
}

// ---- level 1: LDS 4096-bin histogram of bits[31:20] + per-(block,tile) target counts ----
__global__ __launch_bounds__(BT) void k_histA_cnt(const float* __restrict__ depth,
                                                  const float* __restrict__ flow,
                                                  u32* __restrict__ tot1,
                                                  u32* __restrict__ tcnt) {
    __shared__ u32 h[4096];
    __shared__ u32 tc[NT512];
    int tid = threadIdx.x;
    for (int j = tid; j < 4096; j += BT) h[j] = 0;
    for (int j = tid; j < NT512; j += BT) tc[j] = 0;
    __syncthreads();
    for (int v = blockIdx.x * BT + tid; v < NVEC; v += gridDim.x * BT) {
        int i = v * 4;
        float4 d4 = ((const float4*)depth)[v];
        float4 fa = ((const float4*)flow)[v * 2];
        float4 fb = ((const float4*)flow)[v * 2 + 1];
        int y = i / WW, x0 = i - y * WW;   // 4-group never crosses a row (WW%4==0)
        float dd[4] = {d4.x, d4.y, d4.z, d4.w};
        float fx[4] = {fa.x, fa.z, fb.x, fb.z};
        float fy[4] = {fa.y, fa.w, fb.y, fb.w};
        #pragma unroll
        for (int j = 0; j < 4; ++j) {
            if (dd[j] != 100.0f)                                   // sentinel excluded
                atomicAdd(&h[__float_as_uint(dd[j]) >> 20], 1u);   // d>0 -> monotonic bits
            int t = target_of(y, x0 + j, fx[j], fy[j]);
            if (t >= 0) {
                int ty = t / WW, tx = t - ty * WW;
                atomicAdd(&tc[(ty >> 6) * TCX + (tx >> 6)], 1u);
            }
        }
    }
    __syncthreads();
    u32 rep = blockIdx.x & (R1 - 1);
    for (int j = tid; j < 4096; j += BT) {
        u32 v = h[j];
        if (v) atomicAdd(&tot1[rep * 4096 + j], v);   // sparse, short chains
    }
    for (int j = tid; j < NT512; j += BT)
        tcnt[blockIdx.x * NT512 + j] = tc[j];         // non-atomic per-block counts
}

// ---- fused: blocks 0..511 per-tile chunk scan; block 512 quantile select ----
__global__ __launch_bounds__(512) void k_scan_sel(const u32* __restrict__ tcnt,
                                                  const u32* __restrict__ tot1,
                                                  const int* __restrict__ splitp,
                                                  u32* __restrict__ ttot, u32* __restrict__ base2,
                                                  u32* __restrict__ qb1, u32* __restrict__ qr1,
                                                  u32* __restrict__ oidx, u32* __restrict__ obin,
                                                  u32* __restrict__ nown) {
    __shared__ u32 s[512];
    __shared__ u32 qbS[NQ];
    __shared__ u32 totalsh;
    int tid = threadIdx.x;
    if (blockIdx.x < NT512) {
        // ---- tile scan: tile t, 512 chunk counts ----
        int t = blockIdx.x;
        u32 v = tcnt[tid * NT512 + t];
        s[tid] = v;
        __syncthreads();
        for (int off = 1; off < 512; off <<= 1) {
            u32 x = (tid >= off) ? s[tid - off] : 0;
            __syncthreads();
            s[tid] += x;
            __syncthreads();
        }
        base2[tid * NT512 + t] = s[tid] - v;     // [chunk][tile]: coalesced in scatter
        if (tid == 511) ttot[t] = s[511];
        return;
    }
    // ---- quantile select (8 bins/thread over merged 4096-bin hist) ----
    int split = *splitp;
    int base = tid * 8;
    u32 cc[8];
    #pragma unroll
    for (int k = 0; k < 8; ++k) cc[k] = 0;
    for (int r = 0; r < R1; ++r) {
        const u32* tp = tot1 + r * 4096 + base;
        #pragma unroll
        for (int k = 0; k < 8; ++k) cc[k] += tp[k];
    }
    u32 local = 0;
    #pragma unroll
    for (int k = 0; k < 8; ++k) local += cc[k];
    s[tid] = local;
    __syncthreads();
    for (int off = 1; off < 512; off <<= 1) {
        u32 x = (tid >= off) ? s[tid - off] : 0;
        __syncthreads();
        s[tid] += x;
        __syncthreads();
    }
    if (tid == 511) totalsh = s[511];
    __syncthreads();
    u32 l = totalsh;                 // valid-pixel count = histogram sum
    u32 step = l / (u32)split;
    u32 cum = s[tid] - local;        // exclusive prefix of this thread's 8 bins
    for (int k = 0; k < 8; ++k) {
        u32 c = cc[k];
        if (c) {
            for (int q = 0; q <= split; ++q) {
                u32 r = (q < split) ? (u32)q * step : l - 1u;
                if (r >= cum && r < cum + c) {
                    qb1[q] = (u32)(base + k);
                    qr1[q] = r - cum;
                    qbS[q] = (u32)(base + k);
                }
            }
        }
        cum += c;
    }
    __syncthreads();
    if (tid == 0) {   // owners: distinct (adjacent, ascending) hi-12 bins
        int w = -1;
        u32 prev = 0xFFFFFFFFu;
        for (int q = 0; q <= split; ++q) {
            if (qbS[q] != prev) { ++w; prev = qbS[q]; obin[w] = qbS[q]; }
            oidx[q] = (u32)w;
        }
        for (int w2 = w + 1; w2 < MAXOWN; ++w2) obin[w2] = 0xFFFFFFFFu;
        *nown = (u32)(w + 1);
    }
}

// ---- level 2: per-owner LDS hist of bits[19:10]; one block = (chunk, 8-owner group) ----
// Early-out: owners are ascending; range check skips the 8-compare loop for most px.
__global__ __launch_bounds__(1024) void k_ph1(const float* __restrict__ depth,
                                              const u32* __restrict__ obin,
                                              const u32* __restrict__ nownp,
                                              u32* __restrict__ ghist) {
    int c = blockIdx.x / NGRP;          // chunk
    int g = blockIdx.x % NGRP;          // owner group
    int w0 = g * OPB;
    int nown = (int)*nownp;
    if (w0 >= nown) return;
    __shared__ u32 h[OPB * 1024];       // 32 KB
    int tid = threadIdx.x;
    u32 ob[OPB];
    u32 obLo = 0xFFFFFFFFu, obHi = 0;   // valid-owner range (static flow only)
    #pragma unroll
    for (int k = 0; k < OPB; ++k) {
        if (w0 + k < nown) {
            ob[k] = obin[w0 + k];
            if (k == 0) obLo = ob[k];
            obHi = ob[k];
        } else ob[k] = 0xFFFFFFFFu;     // sentinel never matches
    }
    for (int j = tid; j < OPB * 1024; j += 1024) h[j] = 0;
    __syncthreads();
    int lo = c * CH1V, hi = lo + CH1V;
    for (int v = lo + tid; v < hi; v += 1024) {
        float4 d4 = ((const float4*)depth)[v];
        float dd[4] = {d4.x, d4.y, d4.z, d4.w};
        #pragma unroll
        for (int j = 0; j < 4; ++j) {
            u32 bits = __float_as_uint(dd[j]);
            u32 b1 = bits >> 20;
            if (b1 < obLo || b1 > obHi) continue;   // skip compare loop (~most px)
            #pragma unroll
            for (int k = 0; k < OPB; ++k)
                if (ob[k] == b1)
                    atomicAdd(&h[k * 1024 + ((bits >> 10) & 1023u)], 1u);
        }
    }
    __syncthreads();
    for (int j = tid; j < OPB * 1024; j += 1024) {
        int k = j >> 10, bin = j & 1023;
        int w = w0 + k;
        if (w < nown) ghist[(w * NCH1 + c) * 1024 + bin] = h[j];   // non-atomic, coalesced
    }
}

// ---- fused: blocks 0..split red1; block NQ does tile-total prefix -> tbase/tend ----
__global__ __launch_bounds__(1024) void k_red1(const int* __restrict__ splitp,
                                               const u32* __restrict__ qb1,
                                               const u32* __restrict__ qr1,
                                               const u32* __restrict__ oidx,
                                               const u32* __restrict__ ghist,
                                               const u32* __restrict__ ttot,
                                               u32* __restrict__ key22, u32* __restrict__ r2o,
                                               u32* __restrict__ tbase, u32* __restrict__ tend) {
    __shared__ u32 part[1024];
    int tid = threadIdx.x;
    int b = blockIdx.x;
    if (b == NQ) {   // tile-total prefix sum (512 entries)
        u32 tv = (tid < NT512) ? ttot[tid] : 0;
        part[tid] = tv;
        __syncthreads();
        for (int off = 1; off < 1024; off <<= 1) {
            u32 x = (tid >= off) ? part[tid - off] : 0;
            __syncthreads();
            part[tid] += x;
            __syncthreads();
        }
        if (tid < NT512) {
            tbase[tid] = part[tid] - tv;
            tend[tid]  = part[tid];
        }
        return;
    }
    if (b > *splitp) return;
    int w = (int)oidx[b];
    u32 local = 0;
    for (int c = 0; c < NCH1; ++c) local += ghist[(w * NCH1 + c) * 1024 + tid];
    part[tid] = local;
    __syncthreads();
    for (int off = 1; off < 1024; off <<= 1) {
        u32 x = (tid >= off) ? part[tid - off] : 0;
        __syncthreads();
        part[tid] += x;
        __syncthreads();
    }
    u32 target = qr1[b];
    u32 cum = part[tid] - local;
    if (local && target >= cum && target < cum + local) {
        key22[b] = (qb1[b] << 10) | (u32)tid;
        r2o[b] = target - cum;
    }
}

// ---- level 3: low-10-bit histogram restricted to 22-bit keys ----
// Early-out: keys ascending; 2-compare range check skips the 11-loop for ~99.5% px.
__global__ __launch_bounds__(256) void k_ph2(const float* __restrict__ depth,
                                             const int* __restrict__ splitp,
                                             const u32* __restrict__ key22,
                                             u32* __restrict__ gh2) {
    __shared__ u32 k22[NQ];
    int tid = threadIdx.x, split = *splitp;
    if (tid < NQ) k22[tid] = (tid <= split) ? key22[tid] : 0xFFFFFFFFu;
    __syncthreads();
    u32 kmin = k22[0], kmax = k22[split];
    for (int v = blockIdx.x * blockDim.x + tid; v < NVEC; v += gridDim.x * blockDim.x) {
        float4 d4 = ((const float4*)depth)[v];
        float dd[4] = {d4.x, d4.y, d4.z, d4.w};
        #pragma unroll
        for (int j = 0; j < 4; ++j) {
            if (dd[j] != 100.0f) {
                u32 bits = __float_as_uint(dd[j]);
                u32 hi22 = bits >> 10;
                if (hi22 < kmin || hi22 > kmax) continue;   // skip compare loop
                for (int q = 0; q <= split; ++q)
                    if (k22[q] == hi22) atomicAdd(&gh2[q * 1024 + (bits & 1023u)], 1u);
            }
        }
    }
}

// ---- level-3 reduce: exact order-statistic floats ----
__global__ __launch_bounds__(1024) void k_red2(const int* __restrict__ splitp,
                                               const u32* __restrict__ key22,
                                               const u32* __restrict__ r2o,
                                               const u32* __restrict__ gh2,
                                               float* __restrict__ mids) {
    int q = blockIdx.x;
    if (q > *splitp) return;
    __shared__ u32 part[1024];
    int tid = threadIdx.x;
    u32 local = gh2[q * 1024 + tid];
    part[tid] = local;
    __syncthreads();
    for (int off = 1; off < 1024; off <<= 1) {
        u32 v = (tid >= off) ? part[tid - off] : 0;
        __syncthreads();
        part[tid] += v;
        __syncthreads();
    }
    u32 target = r2o[q];
    u32 cum = part[tid] - local;
    if (local && target >= cum && target < cum + local)
        mids[q] = __uint_as_float((key22[q] << 10) | (u32)tid);
}

// ---- scatter: exact-base pair writes, zero device atomics, no inner barriers ----
__global__ __launch_bounds__(BT) void k_scatter(const float* __restrict__ depth,
                                                const float* __restrict__ flow,
                                                const int* __restrict__ splitp,
                                                const float* __restrict__ mids,
                                                const u32* __restrict__ tbase,
                                                const u32* __restrict__ base2,
                                                uint2* __restrict__ pairs) {
    __shared__ u32 cur[NT512];
    __shared__ float msh[NQ];
    int tid = threadIdx.x, split = *splitp;
    if (tid < NQ) msh[tid] = (tid <= split) ? mids[tid] : 0.f;
    if (tid < NT512) cur[tid] = tbase[tid] + base2[blockIdx.x * NT512 + tid];   // coalesced
    __syncthreads();
    float m0 = msh[0], mS = msh[split];
    for (int v = blockIdx.x * BT + tid; v < NVEC; v += gridDim.x * BT) {   // = histA traversal
        int i = v * 4;
        float4 d4 = ((const float4*)depth)[v];
        float4 fa = ((const float4*)flow)[v * 2];
        float4 fb = ((const float4*)flow)[v * 2 + 1];
        int y = i / WW, x0 = i - y * WW;
        float dd[4] = {d4.x, d4.y, d4.z, d4.w};
        float fx[4] = {fa.x, fa.z, fb.x, fb.z};
        float fy[4] = {fa.y, fa.w, fb.y, fb.w};
        #pragma unroll
        for (int j = 0; j < 4; ++j) {
            int t = target_of(y, x0 + j, fx[j], fy[j]);
            if (t < 0) continue;                      // only this drop counted by histA too
            float d = dd[j];
            int rank = -1;
            if (d >= m0 && d < mS) {                  // range early-out (sentinel/max fail it)
                for (int k = 1; k <= split; ++k)
                    if (d < msh[k]) { rank = split - k; break; }   // d>=msh[k-1] implied
            }
            // far bins = low rank; within bin, last row-major source wins.
            // rank<0 (d==max or sentinel): p=0 dummy keeps segments dense, never wins.
            u32 p = (rank >= 0) ? (u32)rank * (u32)NPIX + (u32)(i + j) + 1u : 0u;
            int ty = t / WW, tx = t - ty * WW;
            int tile = (ty >> 6) * TCX + (tx >> 6);
            u32 pos = atomicAdd(&cur[tile], 1u);      // LDS only
            pairs[pos] = make_uint2((u32)t, p);
        }
    }
}

// ---- per-tile LDS z-buffer reduce + output write (contiguous segments) ----
__global__ __launch_bounds__(1024) void k_tile_reduce(const uint2* __restrict__ pairs,
                                                      const u32* __restrict__ tbase,
                                                      const u32* __restrict__ tend,
                                                      const float* __restrict__ img,
                                                      float* __restrict__ out) {
    __shared__ u32 zb[TS * TS];
    int tid = threadIdx.x;
    int tile = blockIdx.x;
    for (int c = tid; c < TS * TS; c += 1024) zb[c] = 0;
    __syncthreads();
    int ty0 = (tile / TCX) << 6, tx0 = (tile % TCX) << 6;
    u32 b = tbase[tile], e = tend[tile];
    for (u32 k = b + tid; k < e; k += 1024) {
        uint2 pr = pairs[k];
        int t = (int)pr.x;
        int ty = t / WW, tx = t - ty * WW;
        atomicMax(&zb[((ty - ty0) << 6) | (tx - tx0)], pr.y);   // LDS
    }
    __syncthreads();
    for (int c = tid; c < TS * TS; c += 1024) {
        int ty = ty0 + (c >> 6);
        if (ty >= HH) continue;
        int tx = tx0 + (c & 63);
        u32 p = zb[c];
        float r = 0.f, g = 0.f, bl = 0.f;
        if (p) {
            u32 src = (p - 1u) % (u32)NPIX;   // p-1 = rank*NPIX + src
            r  = img[src * 3 + 0];
            g  = img[src * 3 + 1];
            bl = img[src * 3 + 2];
        }
        int t = ty * WW + tx;
        out[t * 3 + 0] = r;
        out[t * 3 + 1] = g;
        out[t * 3 + 2] = bl;
    }
}

extern "C" void kernel_launch(void* const* d_in, const int* in_sizes, int n_in,
                              void* d_out, int out_size, void* d_ws, size_t ws_size,
                              hipStream_t stream) {
    const float* img    = (const float*)d_in[0];
    const float* flow   = (const float*)d_in[1];   // [1,H,W,2] flat == [H,W,2]
    const float* depth  = (const float*)d_in[2];
    const int*   splitp = (const int*)d_in[3];

    char* ws = (char*)d_ws;
    float* mids  = (float*)(ws + MIDS_OFF);
    u32*   qb1   = (u32*)(ws + QB1_OFF);
    u32*   qr1   = (u32*)(ws + QR1_OFF);
    u32*   oidx  = (u32*)(ws + OIDX_OFF);
    u32*   obin  = (u32*)(ws + OBIN_OFF);
    u32*   nown  = (u32*)(ws + NOWN_OFF);
    u32*   key22 = (u32*)(ws + KEY22_OFF);
    u32*   r2o   = (u32*)(ws + R2O_OFF);
    u32*   tot1  = (u32*)(ws + TOT1_OFF);
    u32*   gh2   = (u32*)(ws + GH2_OFF);
    u32*   tcnt  = (u32*)(ws + TCNT_OFF);
    u32*   ttot  = (u32*)(ws + TTOT_OFF);
    u32*   tbase = (u32*)(ws + TBASE_OFF);
    u32*   tend  = (u32*)(ws + TEND_OFF);
    u32*   base2 = (u32*)(ws + BASE2_OFF);
    u32*   gh1   = (u32*)(ws + GH1_OFF);
    uint2* pairs = (uint2*)(ws + PAIRS_OFF);
    float* out   = (float*)d_out;

    k_zero       <<<ZBLK, 256, 0, stream>>>((float4*)d_ws);
    k_histA_cnt  <<<NBLK, BT, 0, stream>>>(depth, flow, tot1, tcnt);
    k_scan_sel   <<<NT512 + 1, 512, 0, stream>>>(tcnt, tot1, splitp, ttot, base2,
                                                 qb1, qr1, oidx, obin, nown);
    k_ph1        <<<NCH1 * NGRP, 1024, 0, stream>>>(depth, obin, nown, gh1);
    k_red1       <<<NQ + 1, 1024, 0, stream>>>(splitp, qb1, qr1, oidx, gh1, ttot,
                                               key22, r2o, tbase, tend);
    k_ph2        <<<2048, 256, 0, stream>>>(depth, splitp, key22, gh2);
    k_red2       <<<NQ, 1024, 0, stream>>>(splitp, key22, r2o, gh2, mids);
    k_scatter    <<<NBLK, BT, 0, stream>>>(depth, flow, splitp, mids, tbase, base2, pairs);
    k_tile_reduce<<<NTILE, 1024, 0, stream>>>(pairs, tbase, tend, img, out);
}

// Round 20
// 91.080 us; speedup vs baseline: 1.3567x; 1.0245x over previous
//
#include <hip/hip_runtime.h>

typedef unsigned int u32;

static constexpr int HH = 1080, WW = 1920;
static constexpr int NPIX = HH * WW;            // 2,073,600
static constexpr int NVEC = NPIX / 4;           // 518,400 float4
static constexpr int NQ = 17;                   // supports split <= 16 (actual 10)
static constexpr int MAXOWN = 16;               // max distinct quantile hi-12 bins
static constexpr int OPB = 8;                   // owners per ph1 block (32 KB LDS)
static constexpr int NGRP = MAXOWN / OPB;       // 2 owner groups
static constexpr int NBLK = 512;                // grid for histA / scatter (must match!)
static constexpr int BT   = 1024;               // their block size
static constexpr int R1 = 16;                   // replicas for level-1 bin merge
static constexpr int NCH1 = 128;                // chunks for ph1 (4050 float4 each)
static constexpr int CH1V = NVEC / NCH1;        // 4050
static constexpr int NSUB = 8;                  // red1 stage-A sub-blocks per query
static constexpr int TS = 64;                   // target tile size
static constexpr int TCX = WW / TS;             // 30
static constexpr int TCY = (HH + TS - 1) / TS;  // 17
static constexpr int NTILE = TCX * TCY;         // 510
static constexpr int NT512 = 512;

// ---- workspace layout (bytes; ws_size = 256 MB, plenty) ----
static constexpr size_t MIDS_OFF  = 0;     // float[32]
static constexpr size_t QB1_OFF   = 128;   // u32[32]
static constexpr size_t QR1_OFF   = 256;   // u32[32]
static constexpr size_t OIDX_OFF  = 384;   // u32[32]
static constexpr size_t OBIN_OFF  = 512;   // u32[32]
static constexpr size_t NOWN_OFF  = 640;   // u32[1]
static constexpr size_t KEY22_OFF = 768;   // u32[32]
static constexpr size_t R2O_OFF   = 896;   // u32[32]
static constexpr size_t TOT1_OFF  = 1024;                                   // u32[R1*4096]
static constexpr size_t GH2_OFF   = TOT1_OFF + (size_t)R1 * 4096 * 4;       // u32[NQ*1024]
static constexpr size_t ZERO_BYTES = GH2_OFF + (size_t)NQ * 1024 * 4;       // ~333 KB
static constexpr size_t TCNT_OFF  = ZERO_BYTES;                             // u32[NBLK*512] fully written
static constexpr size_t TTOT_OFF  = TCNT_OFF + (size_t)NBLK * NT512 * 4;    // u32[512]
static constexpr size_t TBASE_OFF = TTOT_OFF + NT512 * 4;                   // u32[512]
static constexpr size_t TEND_OFF  = TBASE_OFF + NT512 * 4;                  // u32[512]
static constexpr size_t BASE2_OFF = TEND_OFF + NT512 * 4;                   // u32[NBLK*512] ([chunk][tile])
static constexpr size_t GH1_OFF   = BASE2_OFF + (size_t)NBLK * NT512 * 4;   // u32[MAXOWN*NCH1*1024]
static constexpr size_t PART1_OFF = GH1_OFF + (size_t)MAXOWN * NCH1 * 1024 * 4; // u32[NQ*NSUB*1024]
static constexpr size_t PAIRS_OFF = PART1_OFF + (size_t)NQ * NSUB * 1024 * 4;   // uint2[NPIX]

static constexpr int ZVEC = (int)(ZERO_BYTES / 16);
static constexpr int ZBLK = (ZVEC + 255) / 256;

// ---- zero header + tot1 + gh2 (own kernel; runtime small-fill is pathological) ----
__global__ __launch_bounds__(256) void k_zero(float4* __restrict__ ws) {
    int i = blockIdx.x * 256 + threadIdx.x;
    if (i < ZVEC) ws[i] = make_float4(0.f, 0.f, 0.f, 0.f);
}

// ---- geometry helper: target pixel index, or -1 if dropped (flow-only) ----
__device__ __forceinline__ int target_of(int y, int x, float fx, float fy) {
    int ty = (int)rintf((float)y + fy);  // rintf = round-half-even = jnp.round
    int tx = (int)rintf((float)x + fx);
    if (ty < 0) ty += HH;                // JAX normalizes negative indices once
    if (tx < 0) tx += WW;
    if ((unsigned)ty >= (unsigned)HH || (unsigned)tx >= (unsigned)WW) return -1;
    return ty * WW + tx;
}

// ---- level 1: LDS 4096-bin histogram of bits[31:20] + per-(block,tile) target counts ----
__global__ __launch_bounds__(BT) void k_histA_cnt(const float* __restrict__ depth,
                                                  const float* __restrict__ flow,
                                                  u32* __restrict__ tot1,
                                                  u32* __restrict__ tcnt) {
    __shared__ u32 h[4096];
    __shared__ u32 tc[NT512];
    int tid = threadIdx.x;
    for (int j = tid; j < 4096; j += BT) h[j] = 0;
    for (int j = tid; j < NT512; j += BT) tc[j] = 0;
    __syncthreads();
    for (int v = blockIdx.x * BT + tid; v < NVEC; v += gridDim.x * BT) {
        int i = v * 4;
        float4 d4 = ((const float4*)depth)[v];
        float4 fa = ((const float4*)flow)[v * 2];
        float4 fb = ((const float4*)flow)[v * 2 + 1];
        int y = i / WW, x0 = i - y * WW;   // 4-group never crosses a row (WW%4==0)
        float dd[4] = {d4.x, d4.y, d4.z, d4.w};
        float fx[4] = {fa.x, fa.z, fb.x, fb.z};
        float fy[4] = {fa.y, fa.w, fb.y, fb.w};
        #pragma unroll
        for (int j = 0; j < 4; ++j) {
            if (dd[j] != 100.0f)                                   // sentinel excluded
                atomicAdd(&h[__float_as_uint(dd[j]) >> 20], 1u);   // d>0 -> monotonic bits
            int t = target_of(y, x0 + j, fx[j], fy[j]);
            if (t >= 0) {
                int ty = t / WW, tx = t - ty * WW;
                atomicAdd(&tc[(ty >> 6) * TCX + (tx >> 6)], 1u);
            }
        }
    }
    __syncthreads();
    u32 rep = blockIdx.x & (R1 - 1);
    for (int j = tid; j < 4096; j += BT) {
        u32 v = h[j];
        if (v) atomicAdd(&tot1[rep * 4096 + j], v);   // sparse, short chains
    }
    for (int j = tid; j < NT512; j += BT)
        tcnt[blockIdx.x * NT512 + j] = tc[j];         // non-atomic per-block counts
}

// ---- fused: blocks 0..511 per-tile chunk scan; block 512 quantile select ----
__global__ __launch_bounds__(512) void k_scan_sel(const u32* __restrict__ tcnt,
                                                  const u32* __restrict__ tot1,
                                                  const int* __restrict__ splitp,
                                                  u32* __restrict__ ttot, u32* __restrict__ base2,
                                                  u32* __restrict__ qb1, u32* __restrict__ qr1,
                                                  u32* __restrict__ oidx, u32* __restrict__ obin,
                                                  u32* __restrict__ nown) {
    __shared__ u32 s[512];
    __shared__ u32 qbS[NQ];
    __shared__ u32 totalsh;
    int tid = threadIdx.x;
    if (blockIdx.x < NT512) {
        // ---- tile scan: tile t, 512 chunk counts ----
        int t = blockIdx.x;
        u32 v = tcnt[tid * NT512 + t];
        s[tid] = v;
        __syncthreads();
        for (int off = 1; off < 512; off <<= 1) {
            u32 x = (tid >= off) ? s[tid - off] : 0;
            __syncthreads();
            s[tid] += x;
            __syncthreads();
        }
        base2[tid * NT512 + t] = s[tid] - v;     // [chunk][tile]: coalesced in scatter
        if (tid == 511) ttot[t] = s[511];
        return;
    }
    // ---- quantile select (8 bins/thread over merged 4096-bin hist) ----
    int split = *splitp;
    int base = tid * 8;
    u32 cc[8];
    #pragma unroll
    for (int k = 0; k < 8; ++k) cc[k] = 0;
    for (int r = 0; r < R1; ++r) {
        const u32* tp = tot1 + r * 4096 + base;
        #pragma unroll
        for (int k = 0; k < 8; ++k) cc[k] += tp[k];
    }
    u32 local = 0;
    #pragma unroll
    for (int k = 0; k < 8; ++k) local += cc[k];
    s[tid] = local;
    __syncthreads();
    for (int off = 1; off < 512; off <<= 1) {
        u32 x = (tid >= off) ? s[tid - off] : 0;
        __syncthreads();
        s[tid] += x;
        __syncthreads();
    }
    if (tid == 511) totalsh = s[511];
    __syncthreads();
    u32 l = totalsh;                 // valid-pixel count = histogram sum
    u32 step = l / (u32)split;
    u32 cum = s[tid] - local;        // exclusive prefix of this thread's 8 bins
    for (int k = 0; k < 8; ++k) {
        u32 c = cc[k];
        if (c) {
            for (int q = 0; q <= split; ++q) {
                u32 r = (q < split) ? (u32)q * step : l - 1u;
                if (r >= cum && r < cum + c) {
                    qb1[q] = (u32)(base + k);
                    qr1[q] = r - cum;
                    qbS[q] = (u32)(base + k);
                }
            }
        }
        cum += c;
    }
    __syncthreads();
    if (tid == 0) {   // owners: distinct (adjacent, ascending) hi-12 bins
        int w = -1;
        u32 prev = 0xFFFFFFFFu;
        for (int q = 0; q <= split; ++q) {
            if (qbS[q] != prev) { ++w; prev = qbS[q]; obin[w] = qbS[q]; }
            oidx[q] = (u32)w;
        }
        for (int w2 = w + 1; w2 < MAXOWN; ++w2) obin[w2] = 0xFFFFFFFFu;
        *nown = (u32)(w + 1);
    }
}

// ---- level 2: per-owner LDS hist of bits[19:10]; one block = (chunk, 8-owner group) ----
// Early-out: owners are ascending; range check skips the 8-compare loop for most px.
__global__ __launch_bounds__(1024) void k_ph1(const float* __restrict__ depth,
                                              const u32* __restrict__ obin,
                                              const u32* __restrict__ nownp,
                                              u32* __restrict__ ghist) {
    int c = blockIdx.x / NGRP;          // chunk
    int g = blockIdx.x % NGRP;          // owner group
    int w0 = g * OPB;
    int nown = (int)*nownp;
    if (w0 >= nown) return;
    __shared__ u32 h[OPB * 1024];       // 32 KB
    int tid = threadIdx.x;
    u32 ob[OPB];
    u32 obLo = 0xFFFFFFFFu, obHi = 0;   // valid-owner range (static flow only)
    #pragma unroll
    for (int k = 0; k < OPB; ++k) {
        if (w0 + k < nown) {
            ob[k] = obin[w0 + k];
            if (k == 0) obLo = ob[k];
            obHi = ob[k];
        } else ob[k] = 0xFFFFFFFFu;     // sentinel never matches
    }
    for (int j = tid; j < OPB * 1024; j += 1024) h[j] = 0;
    __syncthreads();
    int lo = c * CH1V, hi = lo + CH1V;
    for (int v = lo + tid; v < hi; v += 1024) {
        float4 d4 = ((const float4*)depth)[v];
        float dd[4] = {d4.x, d4.y, d4.z, d4.w};
        #pragma unroll
        for (int j = 0; j < 4; ++j) {
            u32 bits = __float_as_uint(dd[j]);
            u32 b1 = bits >> 20;
            if (b1 < obLo || b1 > obHi) continue;   // skip compare loop (~most px)
            #pragma unroll
            for (int k = 0; k < OPB; ++k)
                if (ob[k] == b1)
                    atomicAdd(&h[k * 1024 + ((bits >> 10) & 1023u)], 1u);
        }
    }
    __syncthreads();
    for (int j = tid; j < OPB * 1024; j += 1024) {
        int k = j >> 10, bin = j & 1023;
        int w = w0 + k;
        if (w < nown) ghist[(w * NCH1 + c) * 1024 + bin] = h[j];   // non-atomic, coalesced
    }
}

// ---- red1 stage A: (query, sub) blocks each sum a 16-chunk slice of gh1 ----
__global__ __launch_bounds__(1024) void k_red1a(const int* __restrict__ splitp,
                                                const u32* __restrict__ oidx,
                                                const u32* __restrict__ ghist,
                                                u32* __restrict__ part1) {
    int b = blockIdx.x;                 // q*NSUB + s
    int q = b / NSUB, s = b % NSUB;
    if (q > *splitp) return;
    int w = (int)oidx[q];
    int tid = threadIdx.x;
    u32 local = 0;
    int c0 = s * (NCH1 / NSUB);
    #pragma unroll 4
    for (int c = c0; c < c0 + NCH1 / NSUB; ++c)
        local += ghist[(w * NCH1 + c) * 1024 + tid];
    part1[b * 1024 + tid] = local;      // non-atomic, coalesced
}

// ---- red1 stage B: blocks 0..split reduce partials + scan + select;
//      block NQ does tile-total prefix -> tbase/tend ----
__global__ __launch_bounds__(1024) void k_red1b(const int* __restrict__ splitp,
                                                const u32* __restrict__ qb1,
                                                const u32* __restrict__ qr1,
                                                const u32* __restrict__ part1,
                                                const u32* __restrict__ ttot,
                                                u32* __restrict__ key22, u32* __restrict__ r2o,
                                                u32* __restrict__ tbase, u32* __restrict__ tend) {
    __shared__ u32 part[1024];
    int tid = threadIdx.x;
    int b = blockIdx.x;
    if (b == NQ) {   // tile-total prefix sum (512 entries)
        u32 tv = (tid < NT512) ? ttot[tid] : 0;
        part[tid] = tv;
        __syncthreads();
        for (int off = 1; off < 1024; off <<= 1) {
            u32 x = (tid >= off) ? part[tid - off] : 0;
            __syncthreads();
            part[tid] += x;
            __syncthreads();
        }
        if (tid < NT512) {
            tbase[tid] = part[tid] - tv;
            tend[tid]  = part[tid];
        }
        return;
    }
    if (b > *splitp) return;
    u32 local = 0;
    #pragma unroll
    for (int s = 0; s < NSUB; ++s) local += part1[(b * NSUB + s) * 1024 + tid];
    part[tid] = local;
    __syncthreads();
    for (int off = 1; off < 1024; off <<= 1) {
        u32 x = (tid >= off) ? part[tid - off] : 0;
        __syncthreads();
        part[tid] += x;
        __syncthreads();
    }
    u32 target = qr1[b];
    u32 cum = part[tid] - local;
    if (local && target >= cum && target < cum + local) {
        key22[b] = (qb1[b] << 10) | (u32)tid;
        r2o[b] = target - cum;
    }
}

// ---- level 3: low-10-bit histogram restricted to 22-bit keys ----
// Early-out: keys ascending; 2-compare range check skips the 11-loop for ~99.5% px.
__global__ __launch_bounds__(256) void k_ph2(const float* __restrict__ depth,
                                             const int* __restrict__ splitp,
                                             const u32* __restrict__ key22,
                                             u32* __restrict__ gh2) {
    __shared__ u32 k22[NQ];
    int tid = threadIdx.x, split = *splitp;
    if (tid < NQ) k22[tid] = (tid <= split) ? key22[tid] : 0xFFFFFFFFu;
    __syncthreads();
    u32 kmin = k22[0], kmax = k22[split];
    for (int v = blockIdx.x * blockDim.x + tid; v < NVEC; v += gridDim.x * blockDim.x) {
        float4 d4 = ((const float4*)depth)[v];
        float dd[4] = {d4.x, d4.y, d4.z, d4.w};
        #pragma unroll
        for (int j = 0; j < 4; ++j) {
            if (dd[j] != 100.0f) {
                u32 bits = __float_as_uint(dd[j]);
                u32 hi22 = bits >> 10;
                if (hi22 < kmin || hi22 > kmax) continue;   // skip compare loop
                for (int q = 0; q <= split; ++q)
                    if (k22[q] == hi22) atomicAdd(&gh2[q * 1024 + (bits & 1023u)], 1u);
            }
        }
    }
}

// ---- level-3 reduce: exact order-statistic floats ----
__global__ __launch_bounds__(1024) void k_red2(const int* __restrict__ splitp,
                                               const u32* __restrict__ key22,
                                               const u32* __restrict__ r2o,
                                               const u32* __restrict__ gh2,
                                               float* __restrict__ mids) {
    int q = blockIdx.x;
    if (q > *splitp) return;
    __shared__ u32 part[1024];
    int tid = threadIdx.x;
    u32 local = gh2[q * 1024 + tid];
    part[tid] = local;
    __syncthreads();
    for (int off = 1; off < 1024; off <<= 1) {
        u32 v = (tid >= off) ? part[tid - off] : 0;
        __syncthreads();
        part[tid] += v;
        __syncthreads();
    }
    u32 target = r2o[q];
    u32 cum = part[tid] - local;
    if (local && target >= cum && target < cum + local)
        mids[q] = __uint_as_float((key22[q] << 10) | (u32)tid);
}

// ---- scatter: exact-base pair writes, zero device atomics, no inner barriers ----
__global__ __launch_bounds__(BT) void k_scatter(const float* __restrict__ depth,
                                                const float* __restrict__ flow,
                                                const int* __restrict__ splitp,
                                                const float* __restrict__ mids,
                                                const u32* __restrict__ tbase,
                                                const u32* __restrict__ base2,
                                                uint2* __restrict__ pairs) {
    __shared__ u32 cur[NT512];
    __shared__ float msh[NQ];
    int tid = threadIdx.x, split = *splitp;
    if (tid < NQ) msh[tid] = (tid <= split) ? mids[tid] : 0.f;
    if (tid < NT512) cur[tid] = tbase[tid] + base2[blockIdx.x * NT512 + tid];   // coalesced
    __syncthreads();
    float m0 = msh[0], mS = msh[split];
    for (int v = blockIdx.x * BT + tid; v < NVEC; v += gridDim.x * BT) {   // = histA traversal
        int i = v * 4;
        float4 d4 = ((const float4*)depth)[v];
        float4 fa = ((const float4*)flow)[v * 2];
        float4 fb = ((const float4*)flow)[v * 2 + 1];
        int y = i / WW, x0 = i - y * WW;
        float dd[4] = {d4.x, d4.y, d4.z, d4.w};
        float fx[4] = {fa.x, fa.z, fb.x, fb.z};
        float fy[4] = {fa.y, fa.w, fb.y, fb.w};
        #pragma unroll
        for (int j = 0; j < 4; ++j) {
            int t = target_of(y, x0 + j, fx[j], fy[j]);
            if (t < 0) continue;                      // only this drop counted by histA too
            float d = dd[j];
            int rank = -1;
            if (d >= m0 && d < mS) {                  // range early-out (sentinel/max fail it)
                for (int k = 1; k <= split; ++k)
                    if (d < msh[k]) { rank = split - k; break; }   // d>=msh[k-1] implied
            }
            // far bins = low rank; within bin, last row-major source wins.
            // rank<0 (d==max or sentinel): p=0 dummy keeps segments dense, never wins.
            u32 p = (rank >= 0) ? (u32)rank * (u32)NPIX + (u32)(i + j) + 1u : 0u;
            int ty = t / WW, tx = t - ty * WW;
            int tile = (ty >> 6) * TCX + (tx >> 6);
            u32 pos = atomicAdd(&cur[tile], 1u);      // LDS only
            pairs[pos] = make_uint2((u32)t, p);
        }
    }
}

// ---- per-tile LDS z-buffer reduce + output write (contiguous segments) ----
__global__ __launch_bounds__(1024) void k_tile_reduce(const uint2* __restrict__ pairs,
                                                      const u32* __restrict__ tbase,
                                                      const u32* __restrict__ tend,
                                                      const float* __restrict__ img,
                                                      float* __restrict__ out) {
    __shared__ u32 zb[TS * TS];
    int tid = threadIdx.x;
    int tile = blockIdx.x;
    for (int c = tid; c < TS * TS; c += 1024) zb[c] = 0;
    __syncthreads();
    int ty0 = (tile / TCX) << 6, tx0 = (tile % TCX) << 6;
    u32 b = tbase[tile], e = tend[tile];
    for (u32 k = b + tid; k < e; k += 1024) {
        uint2 pr = pairs[k];
        int t = (int)pr.x;
        int ty = t / WW, tx = t - ty * WW;
        atomicMax(&zb[((ty - ty0) << 6) | (tx - tx0)], pr.y);   // LDS
    }
    __syncthreads();
    for (int c = tid; c < TS * TS; c += 1024) {
        int ty = ty0 + (c >> 6);
        if (ty >= HH) continue;
        int tx = tx0 + (c & 63);
        u32 p = zb[c];
        float r = 0.f, g = 0.f, bl = 0.f;
        if (p) {
            u32 src = (p - 1u) % (u32)NPIX;   // p-1 = rank*NPIX + src
            r  = img[src * 3 + 0];
            g  = img[src * 3 + 1];
            bl = img[src * 3 + 2];
        }
        int t = ty * WW + tx;
        out[t * 3 + 0] = r;
        out[t * 3 + 1] = g;
        out[t * 3 + 2] = bl;
    }
}

extern "C" void kernel_launch(void* const* d_in, const int* in_sizes, int n_in,
                              void* d_out, int out_size, void* d_ws, size_t ws_size,
                              hipStream_t stream) {
    const float* img    = (const float*)d_in[0];
    const float* flow   = (const float*)d_in[1];   // [1,H,W,2] flat == [H,W,2]
    const float* depth  = (const float*)d_in[2];
    const int*   splitp = (const int*)d_in[3];

    char* ws = (char*)d_ws;
    float* mids  = (float*)(ws + MIDS_OFF);
    u32*   qb1   = (u32*)(ws + QB1_OFF);
    u32*   qr1   = (u32*)(ws + QR1_OFF);
    u32*   oidx  = (u32*)(ws + OIDX_OFF);
    u32*   obin  = (u32*)(ws + OBIN_OFF);
    u32*   nown  = (u32*)(ws + NOWN_OFF);
    u32*   key22 = (u32*)(ws + KEY22_OFF);
    u32*   r2o   = (u32*)(ws + R2O_OFF);
    u32*   tot1  = (u32*)(ws + TOT1_OFF);
    u32*   gh2   = (u32*)(ws + GH2_OFF);
    u32*   tcnt  = (u32*)(ws + TCNT_OFF);
    u32*   ttot  = (u32*)(ws + TTOT_OFF);
    u32*   tbase = (u32*)(ws + TBASE_OFF);
    u32*   tend  = (u32*)(ws + TEND_OFF);
    u32*   base2 = (u32*)(ws + BASE2_OFF);
    u32*   gh1   = (u32*)(ws + GH1_OFF);
    u32*   part1 = (u32*)(ws + PART1_OFF);
    uint2* pairs = (uint2*)(ws + PAIRS_OFF);
    float* out   = (float*)d_out;

    k_zero       <<<ZBLK, 256, 0, stream>>>((float4*)d_ws);
    k_histA_cnt  <<<NBLK, BT, 0, stream>>>(depth, flow, tot1, tcnt);
    k_scan_sel   <<<NT512 + 1, 512, 0, stream>>>(tcnt, tot1, splitp, ttot, base2,
                                                 qb1, qr1, oidx, obin, nown);
    k_ph1        <<<NCH1 * NGRP, 1024, 0, stream>>>(depth, obin, nown, gh1);
    k_red1a      <<<NQ * NSUB, 1024, 0, stream>>>(splitp, oidx, gh1, part1);
    k_red1b      <<<NQ + 1, 1024, 0, stream>>>(splitp, qb1, qr1, part1, ttot,
                                               key22, r2o, tbase, tend);
    k_ph2        <<<2048, 256, 0, stream>>>(depth, splitp, key22, gh2);
    k_red2       <<<NQ, 1024, 0, stream>>>(splitp, key22, r2o, gh2, mids);
    k_scatter    <<<NBLK, BT, 0, stream>>>(depth, flow, splitp, mids, tbase, base2, pairs);
    k_tile_reduce<<<NTILE, 1024, 0, stream>>>(pairs, tbase, tend, img, out);
}